// Round 9
// baseline (1403.562 us; speedup 1.0000x reference)
//
#include <hip/hip_runtime.h>
#include <math.h>

#define NB 64
#define NC 512
#define NT 128
#define NQ 8
#define NV 1024
#define NBIG 4194304      /* NB*NC*NT */
#define IDX_STRIDE 255

typedef _Float16 half_t;
typedef half_t f16x8 __attribute__((ext_vector_type(8)));
typedef float  f32x4 __attribute__((ext_vector_type(4)));

#define SC_MAIN 0.015625f           /* 2^-6  */
#define SC_MID  2.44140625e-4f      /* 2^-12 */

#define GLD16(g, l) __builtin_amdgcn_global_load_lds( \
    (const __attribute__((address_space(1))) unsigned int*)(g), \
    (__attribute__((address_space(3))) unsigned int*)(l), 16, 0, 0)

/* A-side split: W1 = fp16(64v), W2 = fp16((64v - W1)*64)  -> v = W1/64 + W2/4096 + O(2^-24 v) */
__device__ inline void split64(float v, half_t& h1, half_t& h2) {
    half_t a = (half_t)(v * 64.f);
    float r = v * 64.f - (float)a;
    h1 = a;
    h2 = (half_t)(r * 64.f);
}
/* X-side split: X1 = fp16(v), X2 = fp16((v - X1)*64)      -> v = X1 + X2/64 + O(2^-24 v) */
__device__ inline void split1(float v, half_t& h1, half_t& h2) {
    half_t a = (half_t)v;
    float r = v - (float)a;
    h1 = a;
    h2 = (half_t)(r * 64.f);
}

/* ------------------------------------------------ init: counts only ---- */
__global__ void init_kernel(int* __restrict__ counts) {
    int i = blockIdx.x * 256 + threadIdx.x;
    if (i < NQ * NV) counts[i] = 0;
}

/* zero pad rows (t=-1 and t=128) of the Xb (hidden) buffers, once per call */
__global__ void padzero_kernel(half_t* __restrict__ X1, half_t* __restrict__ X2) {
    int b = blockIdx.x;
    int row = blockIdx.y ? 129 : 0;
    int c = threadIdx.x;
    size_t off = ((size_t)b * 130 + row) * NC + c;
    X1[off] = (half_t)0.f; X2[off] = (half_t)0.f;
}

/* --------------------------------------------------- codebook |c|^2 rows */
__global__ void cnorm_kernel(const float* __restrict__ cb, float* __restrict__ cnorm) {
    int wid  = (blockIdx.x * 256 + threadIdx.x) >> 6;
    int lane = threadIdx.x & 63;
    if (wid >= NQ * NV) return;
    const float* row = cb + (size_t)wid * NC;
    float s = 0.f;
    #pragma unroll
    for (int e = 0; e < NC / 64; ++e) { float v = row[lane + e * 64]; s = fmaf(v, v, s); }
    #pragma unroll
    for (int m = 32; m >= 1; m >>= 1) s += __shfl_xor(s, m, 64);
    if (lane == 0) cnorm[wid] = s;
}

/* ------ codebook prep: fp16 2-way split, tiled+swizzled for the GEMM ---- */
__global__ void cbprep_kernel(const float* __restrict__ cb, half_t* __restrict__ CbT) {
    int idx = blockIdx.x * 256 + threadIdx.x;     /* 8*8*8*8192 = 4194304 */
    int e  = idx & 8191;
    int kt = (idx >> 13) & 7;
    int mt = (idx >> 16) & 7;
    int q  = idx >> 19;
    int m = e >> 6, kk = e & 63;
    int ci = kt * 64 + kk;
    int code = mt * 128 + m;
    float v = cb[((size_t)(q * NV + code)) * NC + ci];
    half_t h1, h2;
    split64(v, h1, h2);
    int off = ((m * 128 + kk * 2) ^ ((m & 7) << 4)) >> 1;
    size_t base = ((((size_t)q * 2 + 0) * 8 + mt) * 8 + kt) * 8192 + off;
    CbT[base] = h1;
    CbT[base + (size_t)8 * 8 * 8192] = h2;        /* term stride within q */
}

/* ------------- window-mean downsample of (z - zhat) -> fp16 split ------ */
/* rdz==0 (q=0): zhat is ignored (it is zero by construction)              */
__global__ __launch_bounds__(256) void downsample_split_kernel(
        const float* __restrict__ z, const float* __restrict__ zhat,
        half_t* __restrict__ Xd1, half_t* __restrict__ Xd2,
        int s, int log2s, int rdz) {
    __shared__ float D[64 * 129];
    const int tid = threadIdx.x;
    const int b  = blockIdx.x;           /* 0..63  */
    const int c0 = blockIdx.y << 6;      /* 0..448 */
    const size_t gbase = ((size_t)(b * NC + c0)) * NT;   /* 8192 floats */
    if (rdz) {
        #pragma unroll
        for (int i = 0; i < 8; ++i) {
            int idx4 = (i * 256 + tid) * 4;
            float4 zv = *(const float4*)(z    + gbase + idx4);
            float4 hv = *(const float4*)(zhat + gbase + idx4);
            int cc = idx4 >> 7, t = idx4 & 127;
            float* dp = D + cc * 129 + t;
            dp[0] = zv.x - hv.x; dp[1] = zv.y - hv.y; dp[2] = zv.z - hv.z; dp[3] = zv.w - hv.w;
        }
    } else {
        #pragma unroll
        for (int i = 0; i < 8; ++i) {
            int idx4 = (i * 256 + tid) * 4;
            float4 zv = *(const float4*)(z + gbase + idx4);
            int cc = idx4 >> 7, t = idx4 & 127;
            float* dp = D + cc * 129 + t;
            dp[0] = zv.x; dp[1] = zv.y; dp[2] = zv.z; dp[3] = zv.w;
        }
    }
    __syncthreads();
    const int w = NT >> log2s;
    const float invw = 1.f / (float)w;
    for (int idx = tid; idx < (s << 6); idx += 256) {
        int cc = idx & 63;
        int j  = idx >> 6;
        const float* row = D + cc * 129 + j * w;
        float sum = 0.f;
        for (int i = 0; i < w; ++i) sum += row[i];
        float xd = sum * invw;
        half_t h1, h2;
        split1(xd, h1, h2);
        size_t o = ((size_t)(b * s + j)) * NC + c0 + cc;
        Xd1[o] = h1;
        Xd2[o] = h2;
    }
}

/* ---- quant: fp16x2 MFMA distance GEMM + fused per-block argmin --------- */
__global__ __launch_bounds__(256, 2) void quant_mfma_kernel(
        const half_t* __restrict__ CbTq,
        const half_t* __restrict__ Xd1, const half_t* __restrict__ Xd2,
        const float* __restrict__ cnorm,
        float* __restrict__ pval, int* __restrict__ pidx) {
    __shared__ half_t As1[8192];
    __shared__ half_t As2[8192];
    __shared__ half_t Bs1[4096];
    __shared__ half_t Bs2[4096];
    __shared__ float redv[2][2][2][16];
    __shared__ int   redi[2][2][2][16];
    const int tid = threadIdx.x;
    const int w = tid >> 6, l = tid & 63;
    const int wm = w >> 1, wn = w & 1;
    const int lane16 = l & 15, lhi = l >> 4;
    const int nblk = blockIdx.x, mt = blockIdx.y;
    const int r0 = nblk * 64;
    f32x4 accM[4][2] = {}, accm[4][2] = {};
    const half_t* C1b = CbTq + ((size_t)(0 * 8 + mt)) * (8 * 8192);
    const half_t* C2b = CbTq + ((size_t)(1 * 8 + mt)) * (8 * 8192);
    for (int kt = 0; kt < 8; ++kt) {
        const int ci0 = kt << 6;
        __syncthreads();
        const char* c1src = (const char*)(C1b + (size_t)kt * 8192);
        const char* c2src = (const char*)(C2b + (size_t)kt * 8192);
        #pragma unroll
        for (int i = 0; i < 4; ++i) {
            GLD16(c1src + (i * 256 + tid) * 16, (char*)As1 + i * 4096 + w * 1024);
            GLD16(c2src + (i * 256 + tid) * 16, (char*)As2 + i * 4096 + w * 1024);
        }
        #pragma unroll
        for (int i = 0; i < 2; ++i) {
            int c = i * 256 + tid;
            int n = c >> 3, sub = c & 7;
            size_t soff = ((size_t)(r0 + n)) * NC + ci0 + ((sub ^ (n & 7)) << 3);
            GLD16(Xd1 + soff, (char*)Bs1 + i * 4096 + w * 1024);
            GLD16(Xd2 + soff, (char*)Bs2 + i * 4096 + w * 1024);
        }
        __syncthreads();
        #pragma unroll
        for (int kstep = 0; kstep < 2; ++kstep) {
            const int kb = (kstep * 32 + lhi * 8) * 2;
            f16x8 a1[4], a2[4], b1[2], b2[2];
            #pragma unroll
            for (int im = 0; im < 4; ++im) {
                int m = wm * 64 + im * 16 + lane16;
                int off = (m * 128 + kb) ^ ((m & 7) << 4);
                a1[im] = *(const f16x8*)((const char*)As1 + off);
                a2[im] = *(const f16x8*)((const char*)As2 + off);
            }
            #pragma unroll
            for (int in = 0; in < 2; ++in) {
                int n = wn * 32 + in * 16 + lane16;
                int off = (n * 128 + kb) ^ ((n & 7) << 4);
                b1[in] = *(const f16x8*)((const char*)Bs1 + off);
                b2[in] = *(const f16x8*)((const char*)Bs2 + off);
            }
            #pragma unroll
            for (int im = 0; im < 4; ++im)
                #pragma unroll
                for (int in = 0; in < 2; ++in) {
                    accM[im][in] = __builtin_amdgcn_mfma_f32_16x16x32_f16(a1[im], b1[in], accM[im][in], 0, 0, 0);
                    accm[im][in] = __builtin_amdgcn_mfma_f32_16x16x32_f16(a1[im], b2[in], accm[im][in], 0, 0, 0);
                    accm[im][in] = __builtin_amdgcn_mfma_f32_16x16x32_f16(a2[im], b1[in], accm[im][in], 0, 0, 0);
                }
        }
    }
    float bv[2] = {1e30f, 1e30f};
    int   bi[2] = {0, 0};
    #pragma unroll
    for (int im = 0; im < 4; ++im) {
        int mb = mt * 128 + wm * 64 + im * 16 + lhi * 4;
        float4 cn = *(const float4*)(cnorm + mb);
        const float* cnp = (const float*)&cn;
        #pragma unroll
        for (int in = 0; in < 2; ++in) {
            #pragma unroll
            for (int r = 0; r < 4; ++r) {
                float d = cnp[r] - 2.f * (accM[im][in][r] * SC_MAIN + accm[im][in][r] * SC_MID);
                int code = mb + r;
                if (d < bv[in]) { bv[in] = d; bi[in] = code; }
            }
        }
    }
    #pragma unroll
    for (int m = 16; m <= 32; m <<= 1) {
        #pragma unroll
        for (int in = 0; in < 2; ++in) {
            float ov = __shfl_xor(bv[in], m, 64);
            int   oi = __shfl_xor(bi[in], m, 64);
            if (ov < bv[in] || (ov == bv[in] && oi < bi[in])) { bv[in] = ov; bi[in] = oi; }
        }
    }
    if (lhi == 0) {
        #pragma unroll
        for (int in = 0; in < 2; ++in) { redv[wm][wn][in][lane16] = bv[in]; redi[wm][wn][in][lane16] = bi[in]; }
    }
    __syncthreads();
    if (wm == 0 && lhi == 0) {
        #pragma unroll
        for (int in = 0; in < 2; ++in) {
            float v0 = redv[0][wn][in][lane16]; int i0 = redi[0][wn][in][lane16];
            float v1 = redv[1][wn][in][lane16]; int i1 = redi[1][wn][in][lane16];
            if (v1 < v0 || (v1 == v0 && i1 < i0)) { v0 = v1; i0 = i1; }
            int r = r0 + wn * 32 + in * 16 + lane16;
            pval[(size_t)r * 8 + mt] = v0;
            pidx[(size_t)r * 8 + mt] = i0;
        }
    }
}

/* ------------------------------------- cross-block argmin + idx + counts */
__global__ void argmin_final_kernel(const float* __restrict__ pval, const int* __restrict__ pidx,
                                    int* __restrict__ idx_int, int* __restrict__ counts,
                                    float* __restrict__ out_idx, int R, int s, int log2s, int offq) {
    int r = blockIdx.x * 256 + threadIdx.x;
    if (r >= R) return;
    float bv = 1e30f; int bi = 0;
    #pragma unroll
    for (int k = 0; k < 8; ++k) {
        float v = pval[(size_t)r * 8 + k];
        int   i = pidx[(size_t)r * 8 + k];
        if (v < bv || (v == bv && i < bi)) { bv = v; bi = i; }
    }
    idx_int[r] = bi;
    atomicAdd(&counts[bi], 1);
    int b = r >> log2s, j = r & (s - 1);
    out_idx[(size_t)b * IDX_STRIDE + offq + j] = (float)bi;
}

/* ----------------- upsample + fp16 split, padded Xt layout -------------- */
__global__ void upsample_split_kernel(const float* __restrict__ cb, const int* __restrict__ idx_int,
                                      half_t* __restrict__ X1, half_t* __restrict__ X2, int s) {
    int b = blockIdx.x, tp = blockIdx.y, c = threadIdx.x;
    size_t off = ((size_t)b * 130 + tp) * NC + c;
    if (tp == 0 || tp == 129) { X1[off] = (half_t)0.f; X2[off] = (half_t)0.f; return; }
    int t = tp - 1;
    float in = (t + 0.5f) * ((float)s * (1.f / 128.f)) - 0.5f;
    float jf = floorf(in);
    float f = in - jf;
    int j0 = (int)jf;
    int i0 = min(max(j0, 0), s - 1);
    int i1 = min(max(j0 + 1, 0), s - 1);
    const int* ib = idx_int + b * s;
    float v0 = cb[(size_t)ib[i0] * NC + c];
    float v1 = cb[(size_t)ib[i1] * NC + c];
    float v = (1.f - f) * v0 + f * v1;
    half_t h1, h2;
    split1(v, h1, h2);
    X1[off] = h1; X2[off] = h2;
}

/* ----- weight prep: fp16 2-way split, tile+swizzle for the conv GEMM ---- */
__global__ void wprep_kernel(const float* __restrict__ W /* [2][512][512][3] */,
                             half_t* __restrict__ Wt) {
    int d = blockIdx.y;
    const float* Wd = W + (size_t)d * NC * NC * 3;
    half_t* Wtd = Wt + (size_t)d * (2 * 4 * 24 * 8192);
    int idx = blockIdx.x * 256 + threadIdx.x;      /* 786432 = 4*24*8192 */
    int e  = idx & 8191;
    int rest = idx >> 13;
    int kt = rest % 24;
    int mtl = rest / 24;
    int m = e >> 6, kk = e & 63;
    int k = kt * 64 + kk;
    int ks = k >> 9, ci = k & 511;
    int co = mtl * 128 + m;
    float v = Wd[((size_t)co * NC + ci) * 3 + ks];
    half_t h1, h2;
    split64(v, h1, h2);
    int off = ((m * 128 + kk * 2) ^ ((m & 7) << 4)) >> 1;
    size_t base = ((size_t)mtl * 24 + kt) * 8192 + off;
    Wtd[base] = h1;
    Wtd[base + (size_t)4 * 24 * 8192] = h2;
}

/* -- conv1d fp16x2 MFMA GEMM: A via LDS dbuf, B direct global->regs ------ */
/* 512 thr, tile 128m x 128n, grid (64 b, 4 mt), k-split waves 2m x 2n x 2k */
/* MODE 0: y=relu(...); split -> Y1/Y2.  MODE 1: zhat update + loss.       */
/* FIRST (MODE 1 only): write zhat = y (no read) for q==0.                 */
template<int MODE, int FIRST>
__global__ __launch_bounds__(512) void conv_mfma_kernel(
        const half_t* __restrict__ Wt,
        const half_t* __restrict__ X1, const half_t* __restrict__ X2,
        const float* __restrict__ bias,
        half_t* __restrict__ Y1, half_t* __restrict__ Y2,
        float* __restrict__ zhat, const float* __restrict__ z,
        float* __restrict__ lpart) {
    __shared__ __align__(16) half_t A1a[8192], A2a[8192];
    __shared__ __align__(16) half_t A1b[8192], A2b[8192];
    const int tid = threadIdx.x;
    const int w = tid >> 6;
    const int wk = w >> 2;                        /* k-group 0/1          */
    const int wm = (w >> 1) & 1, wn = w & 1;      /* 2m x 2n of 64x64     */
    const int p  = w & 3;                         /* (wm,wn) pair id      */
    const int l = tid & 63, lane16 = l & 15, lhi = l >> 4;
    const int b = blockIdx.x, mt = blockIdx.y;
    f32x4 accM[4][4] = {}, accm[4][4] = {};
    const half_t* W1b = Wt + ((size_t)(0 * 4 + mt)) * (24 * 8192);
    const half_t* W2b = Wt + ((size_t)(1 * 4 + mt)) * (24 * 8192);
    const int kbB = wk * 64 + lhi * 16;           /* byte off in A k-dim  */
    const int cibase = wk * 32 + lhi * 8;         /* halfs: this wave's K */

    auto stageA = [&](half_t* dA1, half_t* dA2, int kt) {
        const char* s1 = (const char*)(W1b + (size_t)kt * 8192);
        const char* s2 = (const char*)(W2b + (size_t)kt * 8192);
        #pragma unroll
        for (int i = 0; i < 2; ++i) {
            int doff = i * 8192 + w * 1024;
            GLD16(s1 + (i * 512 + tid) * 16, (char*)dA1 + doff);
            GLD16(s2 + (i * 512 + tid) * 16, (char*)dA2 + doff);
        }
    };
    auto ldB = [&](f16x8* d1, f16x8* d2, int kt) {
        const int ks = kt >> 3;
        const int ci = ((kt & 7) << 6) + cibase;
        #pragma unroll
        for (int in = 0; in < 4; ++in) {
            int n = wn * 64 + in * 16 + lane16;
            size_t off = (size_t)(b * 130 + ks + n) * NC + ci;
            d1[in] = *(const f16x8*)(X1 + off);
            d2[in] = *(const f16x8*)(X2 + off);
        }
    };
    auto compute = [&](const half_t* A1, const half_t* A2, const f16x8* b1, const f16x8* b2) {
        f16x8 a1[4], a2[4];
        #pragma unroll
        for (int im = 0; im < 4; ++im) {
            int m = wm * 64 + im * 16 + lane16;
            int off = (m * 128 + kbB) ^ ((m & 7) << 4);
            a1[im] = *(const f16x8*)((const char*)A1 + off);
            a2[im] = *(const f16x8*)((const char*)A2 + off);
        }
        __builtin_amdgcn_s_setprio(1);
        #pragma unroll
        for (int im = 0; im < 4; ++im)
            #pragma unroll
            for (int in = 0; in < 4; ++in) {
                accM[im][in] = __builtin_amdgcn_mfma_f32_16x16x32_f16(a1[im], b1[in], accM[im][in], 0, 0, 0);
                accm[im][in] = __builtin_amdgcn_mfma_f32_16x16x32_f16(a1[im], b2[in], accm[im][in], 0, 0, 0);
                accm[im][in] = __builtin_amdgcn_mfma_f32_16x16x32_f16(a2[im], b1[in], accm[im][in], 0, 0, 0);
            }
        __builtin_amdgcn_s_setprio(0);
    };

    f16x8 b1c[4], b2c[4], b1n[4], b2n[4];
    stageA(A1a, A2a, 0);
    ldB(b1c, b2c, 0);
    __syncthreads();
    #pragma unroll 1
    for (int k2 = 0; k2 < 12; ++k2) {
        stageA(A1b, A2b, 2 * k2 + 1);
        ldB(b1n, b2n, 2 * k2 + 1);
        compute(A1a, A2a, b1c, b2c);
        __syncthreads();
        if (k2 < 11) { stageA(A1a, A2a, 2 * k2 + 2); ldB(b1c, b2c, 2 * k2 + 2); }
        compute(A1b, A2b, b1n, b2n);
        __syncthreads();
    }

    /* combine across k-groups: y = accM*SC_MAIN + accm*SC_MID, via LDS */
    f32x4 y[4][4];
    #pragma unroll
    for (int im = 0; im < 4; ++im)
        #pragma unroll
        for (int in = 0; in < 4; ++in)
            #pragma unroll
            for (int r = 0; r < 4; ++r)
                y[im][in][r] = accM[im][in][r] * SC_MAIN + accm[im][in][r] * SC_MID;

    auto store_part = [&](f32x4* arr, int im) {
        #pragma unroll
        for (int in = 0; in < 4; ++in) arr[in * 256 + p * 64 + l] = y[im][in];
    };
    auto load_part = [&](const f32x4* arr, int im) {
        #pragma unroll
        for (int in = 0; in < 4; ++in) {
            f32x4 t = arr[in * 256 + p * 64 + l];
            #pragma unroll
            for (int r = 0; r < 4; ++r) y[im][in][r] += t[r];
        }
    };
    if (wk == 1) {
        store_part((f32x4*)A1a, 0); store_part((f32x4*)A2a, 1);
        store_part((f32x4*)A1b, 2); store_part((f32x4*)A2b, 3);
    }
    __syncthreads();

    float lsum = 0.f;
    if (wk == 0) {
        load_part((const f32x4*)A1a, 0); load_part((const f32x4*)A2a, 1);
        load_part((const f32x4*)A1b, 2); load_part((const f32x4*)A2b, 3);
        /* epilogue: C/D layout col=lane&15 (n), row=lhi*4+reg (m) */
        #pragma unroll
        for (int im = 0; im < 4; ++im) {
            int mb = mt * 128 + wm * 64 + im * 16 + lhi * 4;
            float bs[4];
            #pragma unroll
            for (int r = 0; r < 4; ++r) bs[r] = bias[mb + r];
            #pragma unroll
            for (int in = 0; in < 4; ++in) {
                int t = wn * 64 + in * 16 + lane16;
                if (MODE == 0) {
                    half_t h1v[4], h2v[4];
                    #pragma unroll
                    for (int r = 0; r < 4; ++r) {
                        float yy = y[im][in][r] + bs[r];
                        yy = yy > 0.f ? yy : 0.f;
                        split1(yy, h1v[r], h2v[r]);
                    }
                    size_t rowoff = ((size_t)(b * 130 + 1 + t)) * NC + mb;
                    *(ushort4*)(Y1 + rowoff) = *(const ushort4*)h1v;
                    *(ushort4*)(Y2 + rowoff) = *(const ushort4*)h2v;
                } else {
                    size_t base = ((size_t)b * NC + mb) * NT + t;
                    #pragma unroll
                    for (int r = 0; r < 4; ++r) {
                        float yy = y[im][in][r] + bs[r];
                        yy = yy > 0.f ? yy : 0.f;
                        size_t oi = base + (size_t)r * NT;
                        float zn = FIRST ? yy : (zhat[oi] + yy);
                        zhat[oi] = zn;
                        float d = zn - z[oi];
                        lsum = fmaf(d, d, lsum);
                    }
                }
            }
        }
    }
    if (MODE == 1) {
        __syncthreads();
        float* red = (float*)A1a;
        red[tid] = lsum;
        __syncthreads();
        for (int st = 256; st >= 1; st >>= 1) {
            if (tid < st) red[tid] += red[tid + st];
            __syncthreads();
        }
        if (tid == 0) lpart[blockIdx.y * 64 + blockIdx.x] = red[0];
    }
}

/* ---- all scales: finalize loss + usage + perplexity in ONE launch ------ */
__global__ void scale_final_all_kernel(const float* __restrict__ lpart, const int* __restrict__ counts,
                                       float* __restrict__ outscal) {
    __shared__ float sm[256];
    __shared__ float se[256];
    __shared__ int   su[256];
    int tid = threadIdx.x;
    float aU = 0.f, aL = 0.f, aP = 0.f;
    for (int q = 0; q < NQ; ++q) {
        float invBS = 1.f / (float)(NB << q);
        float ls = lpart[q * 256 + tid];
        int used = 0; float ent = 0.f;
        #pragma unroll
        for (int k = 0; k < 4; ++k) {
            int cv = counts[q * NV + tid + k * 256];
            if (cv > 0) used++;
            float pp = (float)cv * invBS;
            ent = fmaf(pp, logf(pp + 1e-10f), ent);
        }
        sm[tid] = ls; se[tid] = ent; su[tid] = used;
        __syncthreads();
        for (int st = 128; st >= 1; st >>= 1) {
            if (tid < st) { sm[tid] += sm[tid + st]; se[tid] += se[tid + st]; su[tid] += su[tid + st]; }
            __syncthreads();
        }
        if (tid == 0) {
            float m = sm[0] * (1.f / (float)NBIG);
            aL += 0.25f * m + m;
            aU += ((float)su[0] * (1.f / 1024.f)) * 100.f;
            aP += expf(-se[0]);
        }
        __syncthreads();
    }
    if (tid == 0) {
        outscal[0] = aU * 0.125f;
        outscal[1] = aL * 0.125f;
        outscal[2] = aP * 0.125f;
    }
}

/* ====================================================================== */
extern "C" void kernel_launch(void* const* d_in, const int* in_sizes, int n_in,
                              void* d_out, int out_size, void* d_ws, size_t ws_size,
                              hipStream_t stream) {
    const float* z  = (const float*)d_in[0];
    const float* cb = (const float*)d_in[1];
    const float* pw = (const float*)d_in[2];
    const float* pb = (const float*)d_in[3];

    float* zhat     = (float*)d_out;
    float* out_scal = zhat + NBIG;
    float* out_idx  = zhat + NBIG + 3;

    char* w = (char*)d_ws;
    half_t* Xd1 = (half_t*)w;  w += (size_t)8192 * NC * 2;
    half_t* Xd2 = (half_t*)w;  w += (size_t)8192 * NC * 2;
    half_t* Xa1 = (half_t*)w;  w += (size_t)NB * 130 * NC * 2;
    half_t* Xa2 = (half_t*)w;  w += (size_t)NB * 130 * NC * 2;
    half_t* Xb1 = (half_t*)w;  w += (size_t)NB * 130 * NC * 2;
    half_t* Xb2 = (half_t*)w;  w += (size_t)NB * 130 * NC * 2;
    half_t* Wt  = (half_t*)w;  w += (size_t)2 * 2 * 4 * 24 * 8192 * 2;   /* 2 convs */
    half_t* CbT = (half_t*)w;  w += (size_t)NQ * 2 * 8 * 8 * 8192 * 2;
    float* pval  = (float*)w;  w += (size_t)8192 * 8 * 4;
    int*   pidx  = (int*)w;    w += (size_t)8192 * 8 * 4;
    int*   idx_i = (int*)w;    w += (size_t)16384 * 4;
    int*   counts= (int*)w;    w += (size_t)NQ * NV * 4;
    float* cnorm = (float*)w;  w += (size_t)NQ * NV * 4;
    float* lpart = (float*)w;  w += (size_t)NQ * 256 * 4;

    init_kernel<<<32, 256, 0, stream>>>(counts);
    padzero_kernel<<<dim3(64, 2), 512, 0, stream>>>(Xb1, Xb2);
    cnorm_kernel<<<(NQ * NV) / 4, 256, 0, stream>>>(cb, cnorm);
    cbprep_kernel<<<16384, 256, 0, stream>>>(cb, CbT);

    const size_t WT_CONV = (size_t)2 * 4 * 24 * 8192;   /* halves per conv */
    int offq = 0;
    for (int q = 0; q < NQ; ++q) {
        int s = 1 << q;
        int R = NB * s;
        const float* cbq = cb + (size_t)q * NV * NC;
        const float* wq  = pw + (size_t)q * 2 * NC * NC * 3;
        const float* bq0 = pb + (size_t)q * 2 * NC;
        const float* bq1 = bq0 + NC;

        downsample_split_kernel<<<dim3(64, 8), 256, 0, stream>>>(z, zhat, Xd1, Xd2, s, q, q > 0 ? 1 : 0);
        quant_mfma_kernel<<<dim3(R / 64, 8), 256, 0, stream>>>(
            CbT + (size_t)q * 2 * 8 * 8 * 8192, Xd1, Xd2, cnorm + q * NV, pval, pidx);
        argmin_final_kernel<<<(R + 255) / 256, 256, 0, stream>>>(pval, pidx, idx_i,
                                                                 counts + q * NV, out_idx, R, s, q, offq);
        upsample_split_kernel<<<dim3(64, 130), 512, 0, stream>>>(cbq, idx_i, Xa1, Xa2, s);
        wprep_kernel<<<dim3(3072, 2), 256, 0, stream>>>(wq, Wt);
        conv_mfma_kernel<0, 0><<<dim3(64, 4), 512, 0, stream>>>(
            Wt, Xa1, Xa2, bq0, Xb1, Xb2, nullptr, nullptr, nullptr);
        if (q == 0)
            conv_mfma_kernel<1, 1><<<dim3(64, 4), 512, 0, stream>>>(
                Wt + WT_CONV, Xb1, Xb2, bq1, nullptr, nullptr, zhat, z, lpart + q * 256);
        else
            conv_mfma_kernel<1, 0><<<dim3(64, 4), 512, 0, stream>>>(
                Wt + WT_CONV, Xb1, Xb2, bq1, nullptr, nullptr, zhat, z, lpart + q * 256);
        offq += s;
    }
    scale_final_all_kernel<<<1, 256, 0, stream>>>(lpart, counts, out_scal);
}

// Round 10
// 966.158 us; speedup vs baseline: 1.4527x; 1.4527x over previous
//
#include <hip/hip_runtime.h>
#include <math.h>

#define NB 64
#define NC 512
#define NT 128
#define NQ 8
#define NV 1024
#define NBIG 4194304      /* NB*NC*NT */
#define IDX_STRIDE 255

typedef _Float16 half_t;
typedef half_t f16x8 __attribute__((ext_vector_type(8)));
typedef float  f32x4 __attribute__((ext_vector_type(4)));

#define SC_MAIN 0.015625f           /* 2^-6  */
#define SC_MID  2.44140625e-4f      /* 2^-12 */

#define GLD16(g, l) __builtin_amdgcn_global_load_lds( \
    (const __attribute__((address_space(1))) unsigned int*)(g), \
    (__attribute__((address_space(3))) unsigned int*)(l), 16, 0, 0)

/* A-side split: W1 = fp16(64v), W2 = fp16((64v - W1)*64)  -> v = W1/64 + W2/4096 + O(2^-24 v) */
__device__ inline void split64(float v, half_t& h1, half_t& h2) {
    half_t a = (half_t)(v * 64.f);
    float r = v * 64.f - (float)a;
    h1 = a;
    h2 = (half_t)(r * 64.f);
}
/* X-side split: X1 = fp16(v), X2 = fp16((v - X1)*64)      -> v = X1 + X2/64 + O(2^-24 v) */
__device__ inline void split1(float v, half_t& h1, half_t& h2) {
    half_t a = (half_t)v;
    float r = v - (float)a;
    h1 = a;
    h2 = (half_t)(r * 64.f);
}

/* ------------------------------------------------ init: counts only ---- */
__global__ void init_kernel(int* __restrict__ counts) {
    int i = blockIdx.x * 256 + threadIdx.x;
    if (i < NQ * NV) counts[i] = 0;
}

/* zero pad rows (t=-1 and t=128) of the Xb (hidden) buffers, once per call */
__global__ void padzero_kernel(half_t* __restrict__ X1, half_t* __restrict__ X2) {
    int b = blockIdx.x;
    int row = blockIdx.y ? 129 : 0;
    int c = threadIdx.x;
    size_t off = ((size_t)b * 130 + row) * NC + c;
    X1[off] = (half_t)0.f; X2[off] = (half_t)0.f;
}

/* --------------------------------------------------- codebook |c|^2 rows */
__global__ void cnorm_kernel(const float* __restrict__ cb, float* __restrict__ cnorm) {
    int wid  = (blockIdx.x * 256 + threadIdx.x) >> 6;
    int lane = threadIdx.x & 63;
    if (wid >= NQ * NV) return;
    const float* row = cb + (size_t)wid * NC;
    float s = 0.f;
    #pragma unroll
    for (int e = 0; e < NC / 64; ++e) { float v = row[lane + e * 64]; s = fmaf(v, v, s); }
    #pragma unroll
    for (int m = 32; m >= 1; m >>= 1) s += __shfl_xor(s, m, 64);
    if (lane == 0) cnorm[wid] = s;
}

/* ------ codebook prep: fp16 2-way split, tiled+swizzled for the GEMM ---- */
__global__ void cbprep_kernel(const float* __restrict__ cb, half_t* __restrict__ CbT) {
    int idx = blockIdx.x * 256 + threadIdx.x;     /* 8*8*8*8192 = 4194304 */
    int e  = idx & 8191;
    int kt = (idx >> 13) & 7;
    int mt = (idx >> 16) & 7;
    int q  = idx >> 19;
    int m = e >> 6, kk = e & 63;
    int ci = kt * 64 + kk;
    int code = mt * 128 + m;
    float v = cb[((size_t)(q * NV + code)) * NC + ci];
    half_t h1, h2;
    split64(v, h1, h2);
    int off = ((m * 128 + kk * 2) ^ ((m & 7) << 4)) >> 1;
    size_t base = ((((size_t)q * 2 + 0) * 8 + mt) * 8 + kt) * 8192 + off;
    CbT[base] = h1;
    CbT[base + (size_t)8 * 8 * 8192] = h2;        /* term stride within q */
}

/* ------------- window-mean downsample of (z - zhat) -> fp16 split ------ */
/* rdz==0 (q=0): zhat is ignored (it is zero by construction)              */
__global__ __launch_bounds__(256) void downsample_split_kernel(
        const float* __restrict__ z, const float* __restrict__ zhat,
        half_t* __restrict__ Xd1, half_t* __restrict__ Xd2,
        int s, int log2s, int rdz) {
    __shared__ float D[64 * 129];
    const int tid = threadIdx.x;
    const int b  = blockIdx.x;           /* 0..63  */
    const int c0 = blockIdx.y << 6;      /* 0..448 */
    const size_t gbase = ((size_t)(b * NC + c0)) * NT;   /* 8192 floats */
    if (rdz) {
        #pragma unroll
        for (int i = 0; i < 8; ++i) {
            int idx4 = (i * 256 + tid) * 4;
            float4 zv = *(const float4*)(z    + gbase + idx4);
            float4 hv = *(const float4*)(zhat + gbase + idx4);
            int cc = idx4 >> 7, t = idx4 & 127;
            float* dp = D + cc * 129 + t;
            dp[0] = zv.x - hv.x; dp[1] = zv.y - hv.y; dp[2] = zv.z - hv.z; dp[3] = zv.w - hv.w;
        }
    } else {
        #pragma unroll
        for (int i = 0; i < 8; ++i) {
            int idx4 = (i * 256 + tid) * 4;
            float4 zv = *(const float4*)(z + gbase + idx4);
            int cc = idx4 >> 7, t = idx4 & 127;
            float* dp = D + cc * 129 + t;
            dp[0] = zv.x; dp[1] = zv.y; dp[2] = zv.z; dp[3] = zv.w;
        }
    }
    __syncthreads();
    const int w = NT >> log2s;
    const float invw = 1.f / (float)w;
    for (int idx = tid; idx < (s << 6); idx += 256) {
        int cc = idx & 63;
        int j  = idx >> 6;
        const float* row = D + cc * 129 + j * w;
        float sum = 0.f;
        for (int i = 0; i < w; ++i) sum += row[i];
        float xd = sum * invw;
        half_t h1, h2;
        split1(xd, h1, h2);
        size_t o = ((size_t)(b * s + j)) * NC + c0 + cc;
        Xd1[o] = h1;
        Xd2[o] = h2;
    }
}

/* ---- quant: fp16x2 MFMA distance GEMM + fused per-block argmin --------- */
__global__ __launch_bounds__(256, 2) void quant_mfma_kernel(
        const half_t* __restrict__ CbTq,
        const half_t* __restrict__ Xd1, const half_t* __restrict__ Xd2,
        const float* __restrict__ cnorm,
        float* __restrict__ pval, int* __restrict__ pidx) {
    __shared__ half_t As1[8192];
    __shared__ half_t As2[8192];
    __shared__ half_t Bs1[4096];
    __shared__ half_t Bs2[4096];
    __shared__ float redv[2][2][2][16];
    __shared__ int   redi[2][2][2][16];
    const int tid = threadIdx.x;
    const int w = tid >> 6, l = tid & 63;
    const int wm = w >> 1, wn = w & 1;
    const int lane16 = l & 15, lhi = l >> 4;
    const int nblk = blockIdx.x, mt = blockIdx.y;
    const int r0 = nblk * 64;
    f32x4 accM[4][2] = {}, accm[4][2] = {};
    const half_t* C1b = CbTq + ((size_t)(0 * 8 + mt)) * (8 * 8192);
    const half_t* C2b = CbTq + ((size_t)(1 * 8 + mt)) * (8 * 8192);
    for (int kt = 0; kt < 8; ++kt) {
        const int ci0 = kt << 6;
        __syncthreads();
        const char* c1src = (const char*)(C1b + (size_t)kt * 8192);
        const char* c2src = (const char*)(C2b + (size_t)kt * 8192);
        #pragma unroll
        for (int i = 0; i < 4; ++i) {
            GLD16(c1src + (i * 256 + tid) * 16, (char*)As1 + i * 4096 + w * 1024);
            GLD16(c2src + (i * 256 + tid) * 16, (char*)As2 + i * 4096 + w * 1024);
        }
        #pragma unroll
        for (int i = 0; i < 2; ++i) {
            int c = i * 256 + tid;
            int n = c >> 3, sub = c & 7;
            size_t soff = ((size_t)(r0 + n)) * NC + ci0 + ((sub ^ (n & 7)) << 3);
            GLD16(Xd1 + soff, (char*)Bs1 + i * 4096 + w * 1024);
            GLD16(Xd2 + soff, (char*)Bs2 + i * 4096 + w * 1024);
        }
        __syncthreads();
        #pragma unroll
        for (int kstep = 0; kstep < 2; ++kstep) {
            const int kb = (kstep * 32 + lhi * 8) * 2;
            f16x8 a1[4], a2[4], b1[2], b2[2];
            #pragma unroll
            for (int im = 0; im < 4; ++im) {
                int m = wm * 64 + im * 16 + lane16;
                int off = (m * 128 + kb) ^ ((m & 7) << 4);
                a1[im] = *(const f16x8*)((const char*)As1 + off);
                a2[im] = *(const f16x8*)((const char*)As2 + off);
            }
            #pragma unroll
            for (int in = 0; in < 2; ++in) {
                int n = wn * 32 + in * 16 + lane16;
                int off = (n * 128 + kb) ^ ((n & 7) << 4);
                b1[in] = *(const f16x8*)((const char*)Bs1 + off);
                b2[in] = *(const f16x8*)((const char*)Bs2 + off);
            }
            #pragma unroll
            for (int im = 0; im < 4; ++im)
                #pragma unroll
                for (int in = 0; in < 2; ++in) {
                    accM[im][in] = __builtin_amdgcn_mfma_f32_16x16x32_f16(a1[im], b1[in], accM[im][in], 0, 0, 0);
                    accm[im][in] = __builtin_amdgcn_mfma_f32_16x16x32_f16(a1[im], b2[in], accm[im][in], 0, 0, 0);
                    accm[im][in] = __builtin_amdgcn_mfma_f32_16x16x32_f16(a2[im], b1[in], accm[im][in], 0, 0, 0);
                }
        }
    }
    float bv[2] = {1e30f, 1e30f};
    int   bi[2] = {0, 0};
    #pragma unroll
    for (int im = 0; im < 4; ++im) {
        int mb = mt * 128 + wm * 64 + im * 16 + lhi * 4;
        float4 cn = *(const float4*)(cnorm + mb);
        const float* cnp = (const float*)&cn;
        #pragma unroll
        for (int in = 0; in < 2; ++in) {
            #pragma unroll
            for (int r = 0; r < 4; ++r) {
                float d = cnp[r] - 2.f * (accM[im][in][r] * SC_MAIN + accm[im][in][r] * SC_MID);
                int code = mb + r;
                if (d < bv[in]) { bv[in] = d; bi[in] = code; }
            }
        }
    }
    #pragma unroll
    for (int m = 16; m <= 32; m <<= 1) {
        #pragma unroll
        for (int in = 0; in < 2; ++in) {
            float ov = __shfl_xor(bv[in], m, 64);
            int   oi = __shfl_xor(bi[in], m, 64);
            if (ov < bv[in] || (ov == bv[in] && oi < bi[in])) { bv[in] = ov; bi[in] = oi; }
        }
    }
    if (lhi == 0) {
        #pragma unroll
        for (int in = 0; in < 2; ++in) { redv[wm][wn][in][lane16] = bv[in]; redi[wm][wn][in][lane16] = bi[in]; }
    }
    __syncthreads();
    if (wm == 0 && lhi == 0) {
        #pragma unroll
        for (int in = 0; in < 2; ++in) {
            float v0 = redv[0][wn][in][lane16]; int i0 = redi[0][wn][in][lane16];
            float v1 = redv[1][wn][in][lane16]; int i1 = redi[1][wn][in][lane16];
            if (v1 < v0 || (v1 == v0 && i1 < i0)) { v0 = v1; i0 = i1; }
            int r = r0 + wn * 32 + in * 16 + lane16;
            pval[(size_t)r * 8 + mt] = v0;
            pidx[(size_t)r * 8 + mt] = i0;
        }
    }
}

/* ------------------------------------- cross-block argmin + idx + counts */
__global__ void argmin_final_kernel(const float* __restrict__ pval, const int* __restrict__ pidx,
                                    int* __restrict__ idx_int, int* __restrict__ counts,
                                    float* __restrict__ out_idx, int R, int s, int log2s, int offq) {
    int r = blockIdx.x * 256 + threadIdx.x;
    if (r >= R) return;
    float bv = 1e30f; int bi = 0;
    #pragma unroll
    for (int k = 0; k < 8; ++k) {
        float v = pval[(size_t)r * 8 + k];
        int   i = pidx[(size_t)r * 8 + k];
        if (v < bv || (v == bv && i < bi)) { bv = v; bi = i; }
    }
    idx_int[r] = bi;
    atomicAdd(&counts[bi], 1);
    int b = r >> log2s, j = r & (s - 1);
    out_idx[(size_t)b * IDX_STRIDE + offq + j] = (float)bi;
}

/* ----------------- upsample + fp16 split, padded Xt layout -------------- */
__global__ void upsample_split_kernel(const float* __restrict__ cb, const int* __restrict__ idx_int,
                                      half_t* __restrict__ X1, half_t* __restrict__ X2, int s) {
    int b = blockIdx.x, tp = blockIdx.y, c = threadIdx.x;
    size_t off = ((size_t)b * 130 + tp) * NC + c;
    if (tp == 0 || tp == 129) { X1[off] = (half_t)0.f; X2[off] = (half_t)0.f; return; }
    int t = tp - 1;
    float in = (t + 0.5f) * ((float)s * (1.f / 128.f)) - 0.5f;
    float jf = floorf(in);
    float f = in - jf;
    int j0 = (int)jf;
    int i0 = min(max(j0, 0), s - 1);
    int i1 = min(max(j0 + 1, 0), s - 1);
    const int* ib = idx_int + b * s;
    float v0 = cb[(size_t)ib[i0] * NC + c];
    float v1 = cb[(size_t)ib[i1] * NC + c];
    float v = (1.f - f) * v0 + f * v1;
    half_t h1, h2;
    split1(v, h1, h2);
    X1[off] = h1; X2[off] = h2;
}

/* ----- weight prep: fp16 2-way split, tile+swizzle for the conv GEMM ---- */
__global__ void wprep_kernel(const float* __restrict__ W /* [2][512][512][3] */,
                             half_t* __restrict__ Wt) {
    int d = blockIdx.y;
    const float* Wd = W + (size_t)d * NC * NC * 3;
    half_t* Wtd = Wt + (size_t)d * (2 * 4 * 24 * 8192);
    int idx = blockIdx.x * 256 + threadIdx.x;      /* 786432 = 4*24*8192 */
    int e  = idx & 8191;
    int rest = idx >> 13;
    int kt = rest % 24;
    int mtl = rest / 24;
    int m = e >> 6, kk = e & 63;
    int k = kt * 64 + kk;
    int ks = k >> 9, ci = k & 511;
    int co = mtl * 128 + m;
    float v = Wd[((size_t)co * NC + ci) * 3 + ks];
    half_t h1, h2;
    split64(v, h1, h2);
    int off = ((m * 128 + kk * 2) ^ ((m & 7) << 4)) >> 1;
    size_t base = ((size_t)mtl * 24 + kt) * 8192 + off;
    Wtd[base] = h1;
    Wtd[base + (size_t)4 * 24 * 8192] = h2;
}

/* ---- conv1d as fp16x2 MFMA GEMM, k-split waves (2m x 2n x 2k) ---------- */
/* R7 proven structure: LDS dual-staged A and B, stage-ahead dbuf.         */
/* 512 thr, tile 128m x 128n, grid (64 b, 4 mt).                           */
/* MODE 0: y=relu(...); split -> Y1/Y2.  MODE 1: zhat update + loss.       */
/* FIRST (MODE 1 only): write zhat = y (no read) for q==0.                 */
template<int MODE, int FIRST>
__global__ __launch_bounds__(512) void conv_mfma_kernel(
        const half_t* __restrict__ Wt,
        const half_t* __restrict__ X1, const half_t* __restrict__ X2,
        const float* __restrict__ bias,
        half_t* __restrict__ Y1, half_t* __restrict__ Y2,
        float* __restrict__ zhat, const float* __restrict__ z,
        float* __restrict__ lpart) {
    __shared__ __align__(16) half_t A1a[8192], A2a[8192], B1a[8192], B2a[8192];
    __shared__ __align__(16) half_t A1b[8192], A2b[8192], B1b[8192], B2b[8192];
    const int tid = threadIdx.x;
    const int w = tid >> 6;
    const int wk = w >> 2;                        /* k-group 0/1          */
    const int wm = (w >> 1) & 1, wn = w & 1;      /* 2m x 2n of 64x64     */
    const int p  = w & 3;                         /* (wm,wn) pair id      */
    const int l = tid & 63, lane16 = l & 15, lhi = l >> 4;
    const int b = blockIdx.x, mt = blockIdx.y;
    f32x4 accM[4][4] = {}, accm[4][4] = {};
    const half_t* W1b = Wt + ((size_t)(0 * 4 + mt)) * (24 * 8192);
    const half_t* W2b = Wt + ((size_t)(1 * 4 + mt)) * (24 * 8192);
    const int kb = wk * 64 + lhi * 16;            /* this wave's K half   */

    auto stage = [&](half_t* dA1, half_t* dA2, half_t* dB1, half_t* dB2, int kt) {
        const int ks = kt >> 3, ci0 = (kt & 7) << 6;
        const char* s1 = (const char*)(W1b + (size_t)kt * 8192);
        const char* s2 = (const char*)(W2b + (size_t)kt * 8192);
        const int rowb0 = b * 130 + ks;
        #pragma unroll
        for (int i = 0; i < 2; ++i) {
            int doff = i * 8192 + w * 1024;
            GLD16(s1 + (i * 512 + tid) * 16, (char*)dA1 + doff);
            GLD16(s2 + (i * 512 + tid) * 16, (char*)dA2 + doff);
            int c = i * 512 + tid, n = c >> 3, sub = c & 7;
            size_t soff = (size_t)(rowb0 + n) * NC + ci0 + ((sub ^ (n & 7)) << 3);
            GLD16(X1 + soff, (char*)dB1 + doff);
            GLD16(X2 + soff, (char*)dB2 + doff);
        }
    };
    auto compute = [&](const half_t* A1, const half_t* A2, const half_t* B1, const half_t* B2) {
        f16x8 a1[4], a2[4], b1[4], b2[4];
        #pragma unroll
        for (int im = 0; im < 4; ++im) {
            int m = wm * 64 + im * 16 + lane16;
            int off = (m * 128 + kb) ^ ((m & 7) << 4);
            a1[im] = *(const f16x8*)((const char*)A1 + off);
            a2[im] = *(const f16x8*)((const char*)A2 + off);
        }
        #pragma unroll
        for (int in = 0; in < 4; ++in) {
            int n = wn * 64 + in * 16 + lane16;
            int off = (n * 128 + kb) ^ ((n & 7) << 4);
            b1[in] = *(const f16x8*)((const char*)B1 + off);
            b2[in] = *(const f16x8*)((const char*)B2 + off);
        }
        __builtin_amdgcn_s_setprio(1);
        #pragma unroll
        for (int im = 0; im < 4; ++im)
            #pragma unroll
            for (int in = 0; in < 4; ++in) {
                accM[im][in] = __builtin_amdgcn_mfma_f32_16x16x32_f16(a1[im], b1[in], accM[im][in], 0, 0, 0);
                accm[im][in] = __builtin_amdgcn_mfma_f32_16x16x32_f16(a1[im], b2[in], accm[im][in], 0, 0, 0);
                accm[im][in] = __builtin_amdgcn_mfma_f32_16x16x32_f16(a2[im], b1[in], accm[im][in], 0, 0, 0);
            }
        __builtin_amdgcn_s_setprio(0);
    };

    stage(A1a, A2a, B1a, B2a, 0);
    __syncthreads();
    #pragma unroll 1
    for (int k2 = 0; k2 < 12; ++k2) {
        stage(A1b, A2b, B1b, B2b, 2 * k2 + 1);
        compute(A1a, A2a, B1a, B2a);
        __syncthreads();
        if (k2 < 11) stage(A1a, A2a, B1a, B2a, 2 * k2 + 2);
        compute(A1b, A2b, B1b, B2b);
        __syncthreads();
    }

    /* combine across k-groups: y = accM*SC_MAIN + accm*SC_MID, reduce via LDS */
    f32x4 y[4][4];
    #pragma unroll
    for (int im = 0; im < 4; ++im)
        #pragma unroll
        for (int in = 0; in < 4; ++in)
            #pragma unroll
            for (int r = 0; r < 4; ++r)
                y[im][in][r] = accM[im][in][r] * SC_MAIN + accm[im][in][r] * SC_MID;

    auto store_part = [&](f32x4* arr, int im) {
        #pragma unroll
        for (int in = 0; in < 4; ++in) arr[in * 256 + p * 64 + l] = y[im][in];
    };
    auto load_part = [&](const f32x4* arr, int im) {
        #pragma unroll
        for (int in = 0; in < 4; ++in) {
            f32x4 t = arr[in * 256 + p * 64 + l];
            #pragma unroll
            for (int r = 0; r < 4; ++r) y[im][in][r] += t[r];
        }
    };
    if (wk == 1) {
        store_part((f32x4*)A1b, 0); store_part((f32x4*)A2b, 1);
        store_part((f32x4*)B1b, 2); store_part((f32x4*)B2b, 3);
    }
    __syncthreads();

    float lsum = 0.f;
    if (wk == 0) {
        load_part((const f32x4*)A1b, 0); load_part((const f32x4*)A2b, 1);
        load_part((const f32x4*)B1b, 2); load_part((const f32x4*)B2b, 3);
        /* epilogue: C/D layout col=lane&15 (n), row=lhi*4+reg (m) */
        #pragma unroll
        for (int im = 0; im < 4; ++im) {
            int mb = mt * 128 + wm * 64 + im * 16 + lhi * 4;
            float bs[4];
            #pragma unroll
            for (int r = 0; r < 4; ++r) bs[r] = bias[mb + r];
            #pragma unroll
            for (int in = 0; in < 4; ++in) {
                int t = wn * 64 + in * 16 + lane16;
                if (MODE == 0) {
                    half_t h1v[4], h2v[4];
                    #pragma unroll
                    for (int r = 0; r < 4; ++r) {
                        float yy = y[im][in][r] + bs[r];
                        yy = yy > 0.f ? yy : 0.f;
                        split1(yy, h1v[r], h2v[r]);
                    }
                    size_t rowoff = ((size_t)(b * 130 + 1 + t)) * NC + mb;
                    *(ushort4*)(Y1 + rowoff) = *(const ushort4*)h1v;
                    *(ushort4*)(Y2 + rowoff) = *(const ushort4*)h2v;
                } else {
                    size_t base = ((size_t)b * NC + mb) * NT + t;
                    #pragma unroll
                    for (int r = 0; r < 4; ++r) {
                        float yy = y[im][in][r] + bs[r];
                        yy = yy > 0.f ? yy : 0.f;
                        size_t oi = base + (size_t)r * NT;
                        float zn = FIRST ? yy : (zhat[oi] + yy);
                        zhat[oi] = zn;
                        float d = zn - z[oi];
                        lsum = fmaf(d, d, lsum);
                    }
                }
            }
        }
    }
    if (MODE == 1) {
        __syncthreads();
        float* red = (float*)A1a;
        red[tid] = lsum;
        __syncthreads();
        for (int st = 256; st >= 1; st >>= 1) {
            if (tid < st) red[tid] += red[tid + st];
            __syncthreads();
        }
        if (tid == 0) lpart[blockIdx.y * 64 + blockIdx.x] = red[0];
    }
}

/* ---- all scales: finalize loss + usage + perplexity in ONE launch ------ */
__global__ void scale_final_all_kernel(const float* __restrict__ lpart, const int* __restrict__ counts,
                                       float* __restrict__ outscal) {
    __shared__ float sm[256];
    __shared__ float se[256];
    __shared__ int   su[256];
    int tid = threadIdx.x;
    float aU = 0.f, aL = 0.f, aP = 0.f;
    for (int q = 0; q < NQ; ++q) {
        float invBS = 1.f / (float)(NB << q);
        float ls = lpart[q * 256 + tid];
        int used = 0; float ent = 0.f;
        #pragma unroll
        for (int k = 0; k < 4; ++k) {
            int cv = counts[q * NV + tid + k * 256];
            if (cv > 0) used++;
            float pp = (float)cv * invBS;
            ent = fmaf(pp, logf(pp + 1e-10f), ent);
        }
        sm[tid] = ls; se[tid] = ent; su[tid] = used;
        __syncthreads();
        for (int st = 128; st >= 1; st >>= 1) {
            if (tid < st) { sm[tid] += sm[tid + st]; se[tid] += se[tid + st]; su[tid] += su[tid + st]; }
            __syncthreads();
        }
        if (tid == 0) {
            float m = sm[0] * (1.f / (float)NBIG);
            aL += 0.25f * m + m;
            aU += ((float)su[0] * (1.f / 1024.f)) * 100.f;
            aP += expf(-se[0]);
        }
        __syncthreads();
    }
    if (tid == 0) {
        outscal[0] = aU * 0.125f;
        outscal[1] = aL * 0.125f;
        outscal[2] = aP * 0.125f;
    }
}

/* ====================================================================== */
extern "C" void kernel_launch(void* const* d_in, const int* in_sizes, int n_in,
                              void* d_out, int out_size, void* d_ws, size_t ws_size,
                              hipStream_t stream) {
    const float* z  = (const float*)d_in[0];
    const float* cb = (const float*)d_in[1];
    const float* pw = (const float*)d_in[2];
    const float* pb = (const float*)d_in[3];

    float* zhat     = (float*)d_out;
    float* out_scal = zhat + NBIG;
    float* out_idx  = zhat + NBIG + 3;

    char* w = (char*)d_ws;
    half_t* Xd1 = (half_t*)w;  w += (size_t)8192 * NC * 2;
    half_t* Xd2 = (half_t*)w;  w += (size_t)8192 * NC * 2;
    half_t* Xa1 = (half_t*)w;  w += (size_t)NB * 130 * NC * 2;
    half_t* Xa2 = (half_t*)w;  w += (size_t)NB * 130 * NC * 2;
    half_t* Xb1 = (half_t*)w;  w += (size_t)NB * 130 * NC * 2;
    half_t* Xb2 = (half_t*)w;  w += (size_t)NB * 130 * NC * 2;
    half_t* Wt  = (half_t*)w;  w += (size_t)2 * 2 * 4 * 24 * 8192 * 2;   /* 2 convs */
    half_t* CbT = (half_t*)w;  w += (size_t)NQ * 2 * 8 * 8 * 8192 * 2;
    float* pval  = (float*)w;  w += (size_t)8192 * 8 * 4;
    int*   pidx  = (int*)w;    w += (size_t)8192 * 8 * 4;
    int*   idx_i = (int*)w;    w += (size_t)16384 * 4;
    int*   counts= (int*)w;    w += (size_t)NQ * NV * 4;
    float* cnorm = (float*)w;  w += (size_t)NQ * NV * 4;
    float* lpart = (float*)w;  w += (size_t)NQ * 256 * 4;

    init_kernel<<<32, 256, 0, stream>>>(counts);
    padzero_kernel<<<dim3(64, 2), 512, 0, stream>>>(Xb1, Xb2);
    cnorm_kernel<<<(NQ * NV) / 4, 256, 0, stream>>>(cb, cnorm);
    cbprep_kernel<<<16384, 256, 0, stream>>>(cb, CbT);

    const size_t WT_CONV = (size_t)2 * 4 * 24 * 8192;   /* halves per conv */
    int offq = 0;
    for (int q = 0; q < NQ; ++q) {
        int s = 1 << q;
        int R = NB * s;
        const float* cbq = cb + (size_t)q * NV * NC;
        const float* wq  = pw + (size_t)q * 2 * NC * NC * 3;
        const float* bq0 = pb + (size_t)q * 2 * NC;
        const float* bq1 = bq0 + NC;

        downsample_split_kernel<<<dim3(64, 8), 256, 0, stream>>>(z, zhat, Xd1, Xd2, s, q, q > 0 ? 1 : 0);
        quant_mfma_kernel<<<dim3(R / 64, 8), 256, 0, stream>>>(
            CbT + (size_t)q * 2 * 8 * 8 * 8192, Xd1, Xd2, cnorm + q * NV, pval, pidx);
        argmin_final_kernel<<<(R + 255) / 256, 256, 0, stream>>>(pval, pidx, idx_i,
                                                                 counts + q * NV, out_idx, R, s, q, offq);
        upsample_split_kernel<<<dim3(64, 130), 512, 0, stream>>>(cbq, idx_i, Xa1, Xa2, s);
        wprep_kernel<<<dim3(3072, 2), 256, 0, stream>>>(wq, Wt);
        conv_mfma_kernel<0, 0><<<dim3(64, 4), 512, 0, stream>>>(
            Wt, Xa1, Xa2, bq0, Xb1, Xb2, nullptr, nullptr, nullptr);
        if (q == 0)
            conv_mfma_kernel<1, 1><<<dim3(64, 4), 512, 0, stream>>>(
                Wt + WT_CONV, Xb1, Xb2, bq1, nullptr, nullptr, zhat, z, lpart + q * 256);
        else
            conv_mfma_kernel<1, 0><<<dim3(64, 4), 512, 0, stream>>>(
                Wt + WT_CONV, Xb1, Xb2, bq1, nullptr, nullptr, zhat, z, lpart + q * 256);
        offq += s;
    }
    scale_final_all_kernel<<<1, 256, 0, stream>>>(lpart, counts, out_scal);
}